// Round 6
// baseline (263.897 us; speedup 1.0000x reference)
//
#include <hip/hip_runtime.h>
#include <hip/hip_bf16.h>

#define TT    512
#define ISZ   9
#define HH    50
#define NB    16      // batches per block
#define NWAVE 8       // two 16-row tiles per wave (16 tiles = 256 padded rows)
#define NTH   (NWAVE * 64)   // 512 threads
#define KDIM  128
// K layout (bf16, per batch-column):
//   k=2j/2j+1   : h_j hi/lo (j=0..49)    bytes 0..199
//   k=100..103  : dead cols (j=50,51)    bytes 200..207  <- dead-cell write dump
//   k=104+2i/+1 : x_i hi/lo (i=0..8)     bytes 208..243
//   k=122..127  : zero pad
// Bias is carried in the MFMA C-input (exact f32, pre-scaled).

typedef __bf16 bf16x8_t __attribute__((ext_vector_type(8)));
typedef float  f32x4_t  __attribute__((ext_vector_type(4)));

#define L2E  1.44269504088896340736f

// barrier draining ONLY lgkmcnt (ds ops) — vmcnt (x prefetch) stays in flight
#define BAR() asm volatile("s_waitcnt lgkmcnt(0)\n\ts_barrier" ::: "memory")

__device__ __forceinline__ unsigned short bf16_rne(float f) {
  unsigned u = __builtin_bit_cast(unsigned, f);
  unsigned r = (u + 0x7FFFu + ((u >> 16) & 1u)) >> 16;
  return (unsigned short)r;
}
__device__ __forceinline__ unsigned pack_hilo(float v) {
  __bf16 hi = (__bf16)v;
  float  hf = (float)hi;
  __bf16 lo = (__bf16)(v - hf);
  return ((unsigned)__builtin_bit_cast(unsigned short, lo) << 16) |
         (unsigned)__builtin_bit_cast(unsigned short, hi);
}
__device__ __forceinline__ float sg_exp2(float z) { return __builtin_amdgcn_exp2f(z); }
__device__ __forceinline__ float rcp_f(float z)   { return __builtin_amdgcn_rcpf(z); }

__global__ __launch_bounds__(NTH, 1) void lstm_mfma(
    const float* __restrict__ x,
    const float* __restrict__ w_ih,
    const float* __restrict__ w_hh,
    const float* __restrict__ b_ih,
    const float* __restrict__ b_hh,
    const float* __restrict__ fc_w,
    const float* __restrict__ fc_b,
    float* __restrict__ out) {
  __shared__ __align__(16) unsigned short hbuf[2][NB * KDIM];  // 2 x 4096 B
  __shared__ float redbuf[NWAVE][NB];

  const int tid = threadIdx.x;
  const int w   = tid >> 6;          // wave id 0..7; owns tiles w and w+8
  const int l   = tid & 63;
  const int lb  = l & 15;            // batch column
  const int kq  = l >> 4;            // k-quarter 0..3
  const int b0  = blockIdx.x * NB;

  // ---- zero both h buffers
  for (int i = tid; i < (2 * NB * KDIM) / 2; i += NTH)
    reinterpret_cast<unsigned*>(hbuf)[i] = 0u;

  const int xb = tid / ISZ, xi = tid - xb * ISZ;
  const bool xact = (tid < NB * ISZ);
  __syncthreads();
  // ---- x(t=0) into buf0
  if (xact) {
    float xv = x[(size_t)(b0 + xb) * (TT * ISZ) + xi];
    *(unsigned*)((char*)hbuf[0] + (((xb << 8) + 208 + (xi << 2)) ^ ((xb & 7) << 4))) = pack_hilo(xv);
  }

  // ---- static A fragments for both tiles, weights pre-scaled:
  //   i,f,o rows: * -log2e  -> sigma = rcp(1+exp2(acc))
  //   g row     : * 2log2e  -> tanh  = 1 - 2*rcp(1+exp2(acc))
  // Row permutation rp = 4j+g so lane's 4 acc regs = (i,f,g,o) of one j.
  bf16x8_t afrag[2][4];
#pragma unroll
  for (int tt = 0; tt < 2; ++tt) {
    const int rp   = (w + tt * 8) * 16 + lb;
    const int jA   = rp >> 2;
    const int gA   = rp & 3;
    const int rowA = gA * HH + jA;
    const bool liveA = (jA < HH);
    const float scA = (gA == 2) ? (2.0f * L2E) : (-L2E);
#pragma unroll
    for (int ks = 0; ks < 4; ++ks) {
#pragma unroll
      for (int e = 0; e < 8; ++e) {
        const int K = ks * 32 + kq * 8 + e;
        unsigned short bits = 0;
        if (liveA) {
          if (K < 2 * HH)                       bits = bf16_rne(w_hh[rowA * HH + (K >> 1)] * scA);
          else if (K >= 104 && K < 104 + 2*ISZ) bits = bf16_rne(w_ih[rowA * ISZ + ((K - 104) >> 1)] * scA);
        }
        afrag[tt][ks][e] = __builtin_bit_cast(__bf16, bits);
      }
    }
  }

  // ---- per-lane bias C-init (exact f32, pre-scaled) for cells j0, j1
  const int j0 = w * 4 + kq;          // 0..31, always live
  const int j1 = j0 + 32;             // 32..63, dead if >=50
  const bool live1 = (j1 < HH);
  f32x4_t bias0, bias1;
#pragma unroll
  for (int r = 0; r < 4; ++r) {
    const float sc = (r == 2) ? (2.0f * L2E) : (-L2E);
    bias0[r] = (b_ih[r * HH + j0] + b_hh[r * HH + j0]) * sc;
    bias1[r] = live1 ? (b_ih[r * HH + j1] + b_hh[r * HH + j1]) * sc : 0.0f;
  }

  // ---- loop-invariant LDS byte addresses (buf0-relative; buf1 = +0x1000 imm)
  char* const base = (char*)hbuf[0];
  const int swzb = (lb & 7) << 4;
  const int rd0 = ((lb << 8) + 0   + (kq << 4)) ^ swzb;
  const int rd1 = ((lb << 8) + 64  + (kq << 4)) ^ swzb;
  const int rd2 = ((lb << 8) + 128 + (kq << 4)) ^ swzb;
  const int rd3 = ((lb << 8) + 192 + (kq << 4)) ^ swzb;
  const int wo0 = (((lb << 8) + (j0 << 2)) ^ swzb);
  const int j1c = live1 ? j1 : 50;    // dead cells dump into dead col 50
  const int wo1 = (((lb << 8) + (j1c << 2)) ^ swzb);
  const int xwo = (((xb << 8) + 208 + (xi << 2)) ^ ((xb & 7) << 4));

  const float* xp = x + (size_t)(b0 + xb) * (TT * ISZ) + xi;
  float c0 = 0.0f, h0 = 0.0f, c1 = 0.0f, h1 = 0.0f;
  float xv_n = 0.0f;                 // x(t+1); prefetch depth 2
  if (xact) xv_n = xp[ISZ];
  xp += 2 * ISZ;

#define STEP(T, ROFF, WOFF)                                                      \
  {                                                                              \
    float xv_new = 0.0f;                                                         \
    if (xact && (T) + 2 < TT) xv_new = *xp;                                      \
    xp += ISZ;                                                                   \
    BAR();                                                                       \
    bf16x8_t bb0 = *(const bf16x8_t*)(base + rd0 + (ROFF));                      \
    bf16x8_t bb1 = *(const bf16x8_t*)(base + rd1 + (ROFF));                      \
    bf16x8_t bb2 = *(const bf16x8_t*)(base + rd2 + (ROFF));                      \
    bf16x8_t bb3 = *(const bf16x8_t*)(base + rd3 + (ROFF));                      \
    f32x4_t a0 = bias0, b0a = bias1;                                             \
    f32x4_t a1 = {0.f,0.f,0.f,0.f}, b1a = {0.f,0.f,0.f,0.f};                     \
    a0  = __builtin_amdgcn_mfma_f32_16x16x32_bf16(afrag[0][0], bb0, a0,  0,0,0); \
    b0a = __builtin_amdgcn_mfma_f32_16x16x32_bf16(afrag[1][0], bb0, b0a, 0,0,0); \
    a1  = __builtin_amdgcn_mfma_f32_16x16x32_bf16(afrag[0][2], bb2, a1,  0,0,0); \
    b1a = __builtin_amdgcn_mfma_f32_16x16x32_bf16(afrag[1][2], bb2, b1a, 0,0,0); \
    a0  = __builtin_amdgcn_mfma_f32_16x16x32_bf16(afrag[0][1], bb1, a0,  0,0,0); \
    b0a = __builtin_amdgcn_mfma_f32_16x16x32_bf16(afrag[1][1], bb1, b0a, 0,0,0); \
    a1  = __builtin_amdgcn_mfma_f32_16x16x32_bf16(afrag[0][3], bb3, a1,  0,0,0); \
    b1a = __builtin_amdgcn_mfma_f32_16x16x32_bf16(afrag[1][3], bb3, b1a, 0,0,0); \
    {                                                                            \
      const float zi = a0[0] + a1[0], zf = a0[1] + a1[1];                        \
      const float zg = a0[2] + a1[2], zo = a0[3] + a1[3];                        \
      const float iv = rcp_f(1.0f + sg_exp2(zi));                                \
      const float fv = rcp_f(1.0f + sg_exp2(zf));                                \
      const float gv = fmaf(-2.0f, rcp_f(1.0f + sg_exp2(zg)), 1.0f);             \
      const float ov = rcp_f(1.0f + sg_exp2(zo));                                \
      c0 = fmaf(fv, c0, iv * gv);                                                \
      const float tc = fmaf(-2.0f, rcp_f(1.0f + sg_exp2(c0 * (2.0f * L2E))), 1.0f); \
      h0 = ov * tc;                                                              \
      *(unsigned*)(base + wo0 + (WOFF)) = pack_hilo(h0);                         \
    }                                                                            \
    {                                                                            \
      const float zi = b0a[0] + b1a[0], zf = b0a[1] + b1a[1];                    \
      const float zg = b0a[2] + b1a[2], zo = b0a[3] + b1a[3];                    \
      const float iv = rcp_f(1.0f + sg_exp2(zi));                                \
      const float fv = rcp_f(1.0f + sg_exp2(zf));                                \
      const float gv = fmaf(-2.0f, rcp_f(1.0f + sg_exp2(zg)), 1.0f);             \
      const float ov = rcp_f(1.0f + sg_exp2(zo));                                \
      c1 = fmaf(fv, c1, iv * gv);                                                \
      const float tc = fmaf(-2.0f, rcp_f(1.0f + sg_exp2(c1 * (2.0f * L2E))), 1.0f); \
      h1 = ov * tc;                                                              \
      *(unsigned*)(base + wo1 + (WOFF)) = pack_hilo(h1);                         \
    }                                                                            \
    if (xact && (T) + 1 < TT) *(unsigned*)(base + xwo + (WOFF)) = pack_hilo(xv_n); \
    xv_n = xv_new;                                                               \
  }

  for (int t2 = 0; t2 < TT; t2 += 2) {
    STEP(t2,     0x0000, 0x1000);   // read buf0, write buf1
    STEP(t2 + 1, 0x1000, 0x0000);   // read buf1, write buf0
  }
#undef STEP

  // ---- FC epilogue: out[b] = sum_j h_last[j,b]*fc_w[j] + fc_b
  float p = h0 * fc_w[j0];
  if (live1) p += h1 * fc_w[j1];
  p += __shfl_xor(p, 16);
  p += __shfl_xor(p, 32);
  if (l < NB) redbuf[w][l] = p;
  __syncthreads();
  if (tid < NB) {
    float a = fc_b[0];
#pragma unroll
    for (int ww = 0; ww < NWAVE; ++ww) a += redbuf[ww][tid];
    out[b0 + tid] = a;
  }
}

extern "C" void kernel_launch(void* const* d_in, const int* in_sizes, int n_in,
                              void* d_out, int out_size, void* d_ws, size_t ws_size,
                              hipStream_t stream) {
  const float* x    = (const float*)d_in[0];
  const float* w_ih = (const float*)d_in[1];
  const float* w_hh = (const float*)d_in[2];
  const float* b_ih = (const float*)d_in[3];
  const float* b_hh = (const float*)d_in[4];
  const float* fc_w = (const float*)d_in[5];
  const float* fc_b = (const float*)d_in[6];
  float* out = (float*)d_out;
  const int Btot = in_sizes[0] / (TT * ISZ);   // 4096
  dim3 grid(Btot / NB), block(NTH);
  hipLaunchKernelGGL(lstm_mfma, grid, block, 0, stream,
                     x, w_ih, w_hh, b_ih, b_hh, fc_w, fc_b, out);
}

// Round 7
// 252.712 us; speedup vs baseline: 1.0443x; 1.0443x over previous
//
#include <hip/hip_runtime.h>
#include <hip/hip_bf16.h>

#define TT    512
#define ISZ   9
#define HH    50
#define NB    16      // batches per block
#define NWAVE 16      // waves 0-12: one 16-row tile each; waves 13-15: x staging
#define NTH   (NWAVE * 64)   // 1024 threads
#define KDIM  128
// K layout (bf16, per batch-column):
//   k=2j/2j+1   : h_j hi/lo (j=0..49)    bytes 0..199
//   k=100..103  : dead cols (j=50,51)    bytes 200..207  <- dead-cell write dump
//   k=104+2i/+1 : x_i hi/lo (i=0..8)     bytes 208..243
//   k=122..127  : zero pad (A is zero there)
// Bias is carried in the MFMA C-input (exact f32, pre-scaled); the first MFMA
// of each step reads C=bias regs and writes a fresh acc tuple (no init movs).

typedef __bf16 bf16x8_t __attribute__((ext_vector_type(8)));
typedef float  f32x4_t  __attribute__((ext_vector_type(4)));

#define L2E  1.44269504088896340736f

// barrier draining ONLY lgkmcnt (ds ops) — vmcnt (x prefetch) stays in flight
#define BAR() asm volatile("s_waitcnt lgkmcnt(0)\n\ts_barrier" ::: "memory")

__device__ __forceinline__ unsigned short bf16_rne(float f) {
  unsigned u = __builtin_bit_cast(unsigned, f);
  unsigned r = (u + 0x7FFFu + ((u >> 16) & 1u)) >> 16;
  return (unsigned short)r;
}
__device__ __forceinline__ unsigned pack_hilo(float v) {
  __bf16 hi = (__bf16)v;
  float  hf = (float)hi;
  __bf16 lo = (__bf16)(v - hf);
  return ((unsigned)__builtin_bit_cast(unsigned short, lo) << 16) |
         (unsigned)__builtin_bit_cast(unsigned short, hi);
}
__device__ __forceinline__ float sg_exp2(float z) { return __builtin_amdgcn_exp2f(z); }
__device__ __forceinline__ float rcp_f(float z)   { return __builtin_amdgcn_rcpf(z); }

__global__ __launch_bounds__(NTH, 1) void lstm_mfma(
    const float* __restrict__ x,
    const float* __restrict__ w_ih,
    const float* __restrict__ w_hh,
    const float* __restrict__ b_ih,
    const float* __restrict__ b_hh,
    const float* __restrict__ fc_w,
    const float* __restrict__ fc_b,
    float* __restrict__ out) {
  __shared__ __align__(16) unsigned short hbuf[2][NB * KDIM];  // 2 x 4096 B
  __shared__ float redbuf[NWAVE][NB];

  const int tid = threadIdx.x;
  const int w   = tid >> 6;          // wave id; w<13 = compute (tile w), w>=13 = x-stager
  const int l   = tid & 63;
  const int lb  = l & 15;            // batch column
  const int kq  = l >> 4;            // k-quarter 0..3
  const int b0  = blockIdx.x * NB;
  const bool cw = (w < 13);          // compute wave?

  // ---- zero both h buffers
  for (int i = tid; i < (2 * NB * KDIM) / 2; i += NTH)
    reinterpret_cast<unsigned*>(hbuf)[i] = 0u;

  // x-stager mapping (waves 13-15: 192 lanes, 144 active)
  const int xt = tid - 13 * 64;
  const bool xact = (xt >= 0 && xt < NB * ISZ);
  const int xb = xact ? (xt / ISZ) : 0;
  const int xi = xact ? (xt - xb * ISZ) : 0;
  __syncthreads();
  // ---- x(t=0) into buf0
  if (xact) {
    float xv = x[(size_t)(b0 + xb) * (TT * ISZ) + xi];
    *(unsigned*)((char*)hbuf[0] + (((xb << 8) + 208 + (xi << 2)) ^ ((xb & 7) << 4))) = pack_hilo(xv);
  }

  // ---- static A fragment (tile w), weights pre-scaled:
  //   i,f,o rows: * -log2e  -> acc = -z*L2E
  //   g row     : * 2log2e  -> acc = 2z*L2E
  // Row permutation rp = 4j+g so lane's 4 acc regs = (i,f,g,o) of one j.
  bf16x8_t afrag[4];
  {
    const int rp   = w * 16 + lb;
    const int jA   = rp >> 2;
    const int gA   = rp & 3;
    const int rowA = gA * HH + jA;
    const bool liveA = cw && (jA < HH);
    const float scA = (gA == 2) ? (2.0f * L2E) : (-L2E);
#pragma unroll
    for (int ks = 0; ks < 4; ++ks) {
#pragma unroll
      for (int e = 0; e < 8; ++e) {
        const int K = ks * 32 + kq * 8 + e;
        unsigned short bits = 0;
        if (liveA) {
          if (K < 2 * HH)                       bits = bf16_rne(w_hh[rowA * HH + (K >> 1)] * scA);
          else if (K >= 104 && K < 104 + 2*ISZ) bits = bf16_rne(w_ih[rowA * ISZ + ((K - 104) >> 1)] * scA);
        }
        afrag[ks][e] = __builtin_bit_cast(__bf16, bits);
      }
    }
  }

  // ---- per-lane bias C-init (exact f32, pre-scaled) for cell (j0, lb)
  const int j0 = w * 4 + kq;          // tile 12: kq 2,3 -> dead j 50,51
  const bool live0 = cw && (j0 < HH);
  f32x4_t bias0 = {0.f, 0.f, 0.f, 0.f};
  if (live0) {
#pragma unroll
    for (int r = 0; r < 4; ++r) {
      const float sc = (r == 2) ? (2.0f * L2E) : (-L2E);
      bias0[r] = (b_ih[r * HH + j0] + b_hh[r * HH + j0]) * sc;
    }
  }

  // ---- loop-invariant LDS byte addresses (buf0-relative; buf1 = +0x1000 imm)
  char* const base = (char*)hbuf[0];
  const int swzb = (lb & 7) << 4;
  const int rd0 = ((lb << 8) + 0   + (kq << 4)) ^ swzb;
  const int rd1 = ((lb << 8) + 64  + (kq << 4)) ^ swzb;
  const int rd2 = ((lb << 8) + 128 + (kq << 4)) ^ swzb;
  const int rd3 = ((lb << 8) + 192 + (kq << 4)) ^ swzb;
  const int j0c = (j0 <= 51) ? j0 : 51;           // dead j 50/51 -> dead cols
  const int wo0 = (((lb << 8) + (j0c << 2)) ^ swzb);
  const int xwo = (((xb << 8) + 208 + (xi << 2)) ^ ((xb & 7) << 4));

  const float* xp = x + (size_t)(b0 + xb) * (TT * ISZ) + xi;
  float c0 = 0.0f, h0 = 0.0f;
  float xv_n = 0.0f;                 // x(t+1); prefetch depth 2
  if (xact) xv_n = xp[ISZ];
  xp += 2 * ISZ;

#define STEP(T, ROFF, WOFF)                                                      \
  if (cw) {                                                                      \
    BAR();                                                                       \
    bf16x8_t bb0 = *(const bf16x8_t*)(base + rd0 + (ROFF));                      \
    bf16x8_t bb1 = *(const bf16x8_t*)(base + rd1 + (ROFF));                      \
    bf16x8_t bb2 = *(const bf16x8_t*)(base + rd2 + (ROFF));                      \
    bf16x8_t bb3 = *(const bf16x8_t*)(base + rd3 + (ROFF));                      \
    f32x4_t acc;                                                                 \
    acc = __builtin_amdgcn_mfma_f32_16x16x32_bf16(afrag[0], bb0, bias0, 0,0,0);  \
    acc = __builtin_amdgcn_mfma_f32_16x16x32_bf16(afrag[1], bb1, acc,   0,0,0);  \
    acc = __builtin_amdgcn_mfma_f32_16x16x32_bf16(afrag[2], bb2, acc,   0,0,0);  \
    acc = __builtin_amdgcn_mfma_f32_16x16x32_bf16(afrag[3], bb3, acc,   0,0,0);  \
    const float pi = sg_exp2(acc[0]);   /* exp2(-zi*L2E) */                      \
    const float pf = sg_exp2(acc[1]);                                            \
    const float eg = sg_exp2(acc[2]);   /* exp2(+2zg*L2E) */                     \
    const float po = sg_exp2(acc[3]);                                            \
    const float r1 = rcp_f((1.0f + pi) * (1.0f + eg));                           \
    const float fv = rcp_f(1.0f + pf);                                           \
    c0 = fmaf(fv, c0, (eg - 1.0f) * r1);                                         \
    const float ec = sg_exp2(c0 * (2.0f * L2E));                                 \
    const float r2 = rcp_f((1.0f + po) * (1.0f + ec));                           \
    h0 = (ec - 1.0f) * r2;                                                       \
    *(unsigned*)(base + wo0 + (WOFF)) = pack_hilo(h0);                           \
  } else {                                                                       \
    float xv_new = 0.0f;                                                         \
    if (xact && (T) + 2 < TT) xv_new = *xp;                                      \
    xp += ISZ;                                                                   \
    BAR();                                                                       \
    if (xact && (T) + 1 < TT) *(unsigned*)(base + xwo + (WOFF)) = pack_hilo(xv_n); \
    xv_n = xv_new;                                                               \
  }

  for (int t2 = 0; t2 < TT; t2 += 2) {
    STEP(t2,     0x0000, 0x1000);   // read buf0, write buf1
    STEP(t2 + 1, 0x1000, 0x0000);   // read buf1, write buf0
  }
#undef STEP

  // ---- FC epilogue: out[b] = sum_j h_last[j,b]*fc_w[j] + fc_b
  float p = live0 ? h0 * fc_w[j0] : 0.0f;
  p += __shfl_xor(p, 16);
  p += __shfl_xor(p, 32);
  if (l < NB) redbuf[w][l] = p;
  __syncthreads();
  if (tid < NB) {
    float a = fc_b[0];
#pragma unroll
    for (int ww = 0; ww < NWAVE; ++ww) a += redbuf[ww][tid];
    out[b0 + tid] = a;
  }
}

extern "C" void kernel_launch(void* const* d_in, const int* in_sizes, int n_in,
                              void* d_out, int out_size, void* d_ws, size_t ws_size,
                              hipStream_t stream) {
  const float* x    = (const float*)d_in[0];
  const float* w_ih = (const float*)d_in[1];
  const float* w_hh = (const float*)d_in[2];
  const float* b_ih = (const float*)d_in[3];
  const float* b_hh = (const float*)d_in[4];
  const float* fc_w = (const float*)d_in[5];
  const float* fc_b = (const float*)d_in[6];
  float* out = (float*)d_out;
  const int Btot = in_sizes[0] / (TT * ISZ);   // 4096
  dim3 grid(Btot / NB), block(NTH);
  hipLaunchKernelGGL(lstm_mfma, grid, block, 0, stream,
                     x, w_ih, w_hh, b_ih, b_hh, fc_w, fc_b, out);
}

// Round 8
// 183.209 us; speedup vs baseline: 1.4404x; 1.3794x over previous
//
#include <hip/hip_runtime.h>
#include <hip/hip_bf16.h>

#define TT    512
#define ISZ   9
#define HH    50
#define NB    16      // batches per block
#define NWAVE 16      // waves 0-12: one 16-row tile each; waves 13-15: x staging
#define NTH   (NWAVE * 64)   // 1024 threads
#define KDIM  64
// K layout (bf16, per batch-column), buffer stride 128 B, toggle ^0x800:
//   k=j      : h_j bf16 (j=0..49)
//   k=50+i   : x_i bf16 (i=0..8)
//   k=59..63 : zero pad (A zero there; dead cells j=50,51 dump to k=59,60)
// Bias is carried in the MFMA C-input (exact f32, pre-scaled); first MFMA
// seeds from C=bias regs (no acc-init movs).

typedef __bf16 bf16x8_t __attribute__((ext_vector_type(8)));
typedef float  f32x4_t  __attribute__((ext_vector_type(4)));

#define L2E  1.44269504088896340736f

// barrier draining ONLY lgkmcnt (ds ops) — vmcnt (x prefetch) stays in flight
#define BAR() asm volatile("s_waitcnt lgkmcnt(0)\n\ts_barrier" ::: "memory")

__device__ __forceinline__ unsigned short bf16_rne(float f) {
  unsigned u = __builtin_bit_cast(unsigned, f);
  unsigned r = (u + 0x7FFFu + ((u >> 16) & 1u)) >> 16;
  return (unsigned short)r;
}
__device__ __forceinline__ unsigned short bf16h(float v) {
  __bf16 b = (__bf16)v;
  return __builtin_bit_cast(unsigned short, b);
}
__device__ __forceinline__ float sg_exp2(float z) { return __builtin_amdgcn_exp2f(z); }
__device__ __forceinline__ float rcp_f(float z)   { return __builtin_amdgcn_rcpf(z); }

__global__ __launch_bounds__(NTH, 1) void lstm_mfma(
    const float* __restrict__ x,
    const float* __restrict__ w_ih,
    const float* __restrict__ w_hh,
    const float* __restrict__ b_ih,
    const float* __restrict__ b_hh,
    const float* __restrict__ fc_w,
    const float* __restrict__ fc_b,
    float* __restrict__ out) {
  __shared__ __align__(16) unsigned short hbuf[2][NB * KDIM];  // 2 x 2048 B
  __shared__ float redbuf[NWAVE][NB];

  const int tid = threadIdx.x;
  const int w   = tid >> 6;          // wave id; w<13 = compute (tile w), w>=13 = x-stager
  const int l   = tid & 63;
  const int lb  = l & 15;            // batch column
  const int kq  = l >> 4;            // k-quarter 0..3 (16B chunks within 64B half)
  const int b0  = blockIdx.x * NB;
  const bool cw = (w < 13);

  // ---- zero both h buffers
  for (int i = tid; i < (2 * NB * KDIM) / 2; i += NTH)
    reinterpret_cast<unsigned*>(hbuf)[i] = 0u;

  // x-stager mapping (waves 13-15: 192 lanes, 144 active)
  const int xt = tid - 13 * 64;
  const bool xact = (xt >= 0 && xt < NB * ISZ);
  const int xb = xact ? (xt / ISZ) : 0;
  const int xi = xact ? (xt - xb * ISZ) : 0;
  __syncthreads();
  // ---- x(t=0) into buf0
  if (xact) {
    float xv = x[(size_t)(b0 + xb) * (TT * ISZ) + xi];
    *(unsigned short*)((char*)hbuf[0] + (((xb << 7) + ((50 + xi) << 1)) ^ ((xb & 7) << 4))) = bf16h(xv);
  }

  // ---- static A fragment (tile w), weights pre-scaled:
  //   i,f,o rows: * -log2e ; g row: * 2log2e
  // Row permutation rp = 4j+g so lane's 4 acc regs = (i,f,g,o) of one j.
  // Lane holds A[row = rp][K = 32*ks + 8*kq + e].
  bf16x8_t afrag[2];
  {
    const int rp   = w * 16 + lb;
    const int jA   = rp >> 2;
    const int gA   = rp & 3;
    const int rowA = gA * HH + jA;
    const bool liveA = cw && (jA < HH);
    const float scA = (gA == 2) ? (2.0f * L2E) : (-L2E);
#pragma unroll
    for (int ks = 0; ks < 2; ++ks) {
#pragma unroll
      for (int e = 0; e < 8; ++e) {
        const int K = ks * 32 + kq * 8 + e;
        unsigned short bits = 0;
        if (liveA) {
          if (K < HH)                 bits = bf16_rne(w_hh[rowA * HH + K] * scA);
          else if (K < HH + ISZ)      bits = bf16_rne(w_ih[rowA * ISZ + (K - HH)] * scA);
        }
        afrag[ks][e] = __builtin_bit_cast(__bf16, bits);
      }
    }
  }

  // ---- per-lane bias C-init (exact f32, pre-scaled) for cell (j0, lb)
  const int j0 = w * 4 + kq;          // tile 12: kq 2,3 -> dead j 50,51
  const bool live0 = cw && (j0 < HH);
  f32x4_t bias0 = {0.f, 0.f, 0.f, 0.f};
  if (live0) {
#pragma unroll
    for (int r = 0; r < 4; ++r) {
      const float sc = (r == 2) ? (2.0f * L2E) : (-L2E);
      bias0[r] = (b_ih[r * HH + j0] + b_hh[r * HH + j0]) * sc;
    }
  }

  // ---- loop-invariant LDS byte addresses (buf0-relative; buf1 = +0x800 imm)
  char* const base = (char*)hbuf[0];
  const int swzb = (lb & 7) << 4;
  const int rd0 = ((lb << 7) + 0  + (kq << 4)) ^ swzb;
  const int rd1 = ((lb << 7) + 64 + (kq << 4)) ^ swzb;
  const int j0c = (j0 < HH) ? j0 : (j0 + 9);      // dead j 50,51 -> pad cols 59,60
  const int wo0 = (((lb << 7) + (j0c << 1)) ^ swzb);
  const int xwo = (((xb << 7) + ((50 + xi) << 1)) ^ ((xb & 7) << 4));

  const float* xp = x + (size_t)(b0 + xb) * (TT * ISZ) + xi;
  float csc = 0.0f, h0 = 0.0f;       // csc = c * 2*L2E (pre-scaled cell state)
  float xv_n = 0.0f;                 // x(t+1); prefetch depth 2
  if (xact) xv_n = xp[ISZ];
  xp += 2 * ISZ;

#define STEP(T, ROFF, WOFF)                                                      \
  if (cw) {                                                                      \
    BAR();                                                                       \
    bf16x8_t bb0 = *(const bf16x8_t*)(base + rd0 + (ROFF));                      \
    bf16x8_t bb1 = *(const bf16x8_t*)(base + rd1 + (ROFF));                      \
    f32x4_t acc;                                                                 \
    acc = __builtin_amdgcn_mfma_f32_16x16x32_bf16(afrag[0], bb0, bias0, 0,0,0);  \
    acc = __builtin_amdgcn_mfma_f32_16x16x32_bf16(afrag[1], bb1, acc,   0,0,0);  \
    const float pi = sg_exp2(acc[0]);   /* e^-zi  */                             \
    const float pf = sg_exp2(acc[1]);   /* e^-zf  */                             \
    const float eg = sg_exp2(acc[2]);   /* e^+2zg */                             \
    const float po = sg_exp2(acc[3]);   /* e^-zo  */                             \
    const float r1 = rcp_f((1.0f + pi) * (1.0f + eg));                           \
    const float fv = rcp_f(1.0f + pf);                                           \
    const float ig2 = (eg - 1.0f) * r1 * (2.0f * L2E);                           \
    csc = fmaf(fv, csc, ig2);           /* csc = 2*L2E*c */                      \
    const float ec = sg_exp2(csc);                                               \
    const float r2 = rcp_f((1.0f + po) * (1.0f + ec));                           \
    h0 = (ec - 1.0f) * r2;                                                       \
    *(unsigned short*)(base + wo0 + (WOFF)) = bf16h(h0);                         \
  } else {                                                                       \
    float xv_new = 0.0f;                                                         \
    if (xact && (T) + 2 < TT) xv_new = *xp;                                      \
    xp += ISZ;                                                                   \
    BAR();                                                                       \
    if (xact && (T) + 1 < TT) *(unsigned short*)(base + xwo + (WOFF)) = bf16h(xv_n); \
    xv_n = xv_new;                                                               \
  }

  for (int t2 = 0; t2 < TT; t2 += 2) {
    STEP(t2,     0x000, 0x800);   // read buf0, write buf1
    STEP(t2 + 1, 0x800, 0x000);   // read buf1, write buf0
  }
#undef STEP

  // ---- FC epilogue: out[b] = sum_j h_last[j,b]*fc_w[j] + fc_b
  float p = live0 ? h0 * fc_w[j0] : 0.0f;
  p += __shfl_xor(p, 16);
  p += __shfl_xor(p, 32);
  if (l < NB) redbuf[w][l] = p;
  __syncthreads();
  if (tid < NB) {
    float a = fc_b[0];
#pragma unroll
    for (int ww = 0; ww < NWAVE; ++ww) a += redbuf[ww][tid];
    out[b0 + tid] = a;
  }
}

extern "C" void kernel_launch(void* const* d_in, const int* in_sizes, int n_in,
                              void* d_out, int out_size, void* d_ws, size_t ws_size,
                              hipStream_t stream) {
  const float* x    = (const float*)d_in[0];
  const float* w_ih = (const float*)d_in[1];
  const float* w_hh = (const float*)d_in[2];
  const float* b_ih = (const float*)d_in[3];
  const float* b_hh = (const float*)d_in[4];
  const float* fc_w = (const float*)d_in[5];
  const float* fc_b = (const float*)d_in[6];
  float* out = (float*)d_out;
  const int Btot = in_sizes[0] / (TT * ISZ);   // 4096
  dim3 grid(Btot / NB), block(NTH);
  hipLaunchKernelGGL(lstm_mfma, grid, block, 0, stream,
                     x, w_ih, w_hh, b_ih, b_hh, fc_w, fc_b, out);
}